// Round 4
// baseline (375.053 us; speedup 1.0000x reference)
//
#include <hip/hip_runtime.h>

#define THREADS 256

typedef float v4f __attribute__((ext_vector_type(4)));

// ---------------- CSR build ----------------

// counts + per-target rank (atomic return value) -> scatter needs no atomics
__global__ __launch_bounds__(THREADS) void k_hist2(const int* __restrict__ tgt,
                                                   int* __restrict__ cnt,
                                                   int* __restrict__ ke, int E) {
    int e = blockIdx.x * THREADS + threadIdx.x;
    if (e < E) ke[e] = atomicAdd(&cnt[tgt[e]], 1);
}

// counts only (tier without ke array)
__global__ __launch_bounds__(THREADS) void k_hist(const int* __restrict__ tgt,
                                                  int* __restrict__ cnt, int E) {
    int e = blockIdx.x * THREADS + threadIdx.x;
    if (e < E) atomicAdd(&cnt[tgt[e]], 1);
}

__global__ __launch_bounds__(THREADS) void k_scan_partial(const int* __restrict__ cnt,
                                                          int* __restrict__ bsum, int N) {
    __shared__ int lds[THREADS];
    int base = blockIdx.x * 1024 + threadIdx.x * 4;
    int s = 0;
    #pragma unroll
    for (int k = 0; k < 4; ++k) { int i = base + k; if (i < N) s += cnt[i]; }
    lds[threadIdx.x] = s; __syncthreads();
    for (int off = THREADS / 2; off > 0; off >>= 1) {
        if (threadIdx.x < off) lds[threadIdx.x] += lds[threadIdx.x + off];
        __syncthreads();
    }
    if (threadIdx.x == 0) bsum[blockIdx.x] = lds[0];
}

__global__ __launch_bounds__(1024) void k_scan_bsum(int* __restrict__ bsum, int NB) {
    __shared__ int lds[1024];
    int t = threadIdx.x;
    int v = (t < NB) ? bsum[t] : 0;
    lds[t] = v; __syncthreads();
    for (int off = 1; off < 1024; off <<= 1) {
        int x = (t >= off) ? lds[t - off] : 0;
        __syncthreads();
        lds[t] += x;
        __syncthreads();
    }
    if (t < NB) bsum[t] = lds[t] - v;   // exclusive
}

// writes rowptr AND re-initializes cnt[i] = rowptr[i] (cursor for atomic-tier scatter)
__global__ __launch_bounds__(THREADS) void k_scan_final(int* __restrict__ cnt,
                                                        const int* __restrict__ bsum,
                                                        int* __restrict__ rowptr,
                                                        int N, int E) {
    __shared__ int lds[THREADS];
    int base = blockIdx.x * 1024 + threadIdx.x * 4;
    int v[4]; int local = 0;
    #pragma unroll
    for (int k = 0; k < 4; ++k) {
        int i = base + k;
        v[k] = (i < N) ? cnt[i] : 0;
        local += v[k];
    }
    lds[threadIdx.x] = local; __syncthreads();
    for (int off = 1; off < THREADS; off <<= 1) {
        int x = (threadIdx.x >= off) ? lds[threadIdx.x - off] : 0;
        __syncthreads();
        lds[threadIdx.x] += x;
        __syncthreads();
    }
    int p = lds[threadIdx.x] - local + bsum[blockIdx.x];
    #pragma unroll
    for (int k = 0; k < 4; ++k) {
        int i = base + k;
        if (i < N) { rowptr[i] = p; cnt[i] = p; p += v[k]; }
    }
    if (blockIdx.x == 0 && threadIdx.x == 0) rowptr[N] = E;
}

// ---------------- node table transpose: [N][32] -> [N][8]{f0,x,y,z} ----------------
// per-edge node gather in agg becomes 8 lanes x 16B = one coalesced 128B line

__global__ __launch_bounds__(THREADS) void k_ntrans(const float* __restrict__ node,
                                                    float* __restrict__ nodeT, int NT8) {
    int t = blockIdx.x * THREADS + threadIdx.x;   // t = n*8 + i
    if (t >= NT8) return;
    int n = t >> 3, i = t & 7;
    const float* nr = node + (size_t)n * 32;
    v4f v;
    v[0] = nr[i];
    v[1] = nr[8 + 3*i + 0];
    v[2] = nr[8 + 3*i + 1];
    v[3] = nr[8 + 3*i + 2];
    *(v4f*)(nodeT + (size_t)t * 4) = v;
}

// ---------------- scatter payload into CSR order (full 64B rows) ----------------
// payload row (16 floats, 64B): [s,u0,u1,u2 | Q00,Q01,Q02,Q11 | Q12,Q22,src,0 | 0,0,0,0]
// ke!=null: pos = rowptr[tgt]+ke[e] (NO atomics here -- R3 measured atomic cursor adds
// ~48MB of RMW write traffic to the write-bound scatter). Random 64B writes pay no
// line-fill (R0: WRITE_SIZE == payload bytes). Plain stores so L2 merges the 4x16B.

__global__ __launch_bounds__(THREADS) void k_scatter4(const int* __restrict__ eidx,
                                                      const int* __restrict__ ke,    // null => atomic
                                                      const int* __restrict__ rowptr,
                                                      int* __restrict__ cursor,
                                                      const float* __restrict__ sh0,
                                                      const float* __restrict__ sh1,
                                                      const float* __restrict__ sh2,
                                                      float* __restrict__ pay,
                                                      int E) {
    int e = blockIdx.x * THREADS + threadIdx.x;
    if (e >= E) return;

    constexpr float IS10 = 0.31622776601683794f;
    constexpr float IS30 = 0.18257418583505536f;

    const int src = eidx[e];
    const int tgt = eidx[E + e];
    int pos;
    if (ke) pos = rowptr[tgt] + ke[e];
    else    pos = atomicAdd(&cursor[tgt], 1);

    const float s  = __builtin_nontemporal_load(&sh0[e]);
    const float u0 = __builtin_nontemporal_load(&sh1[3*e+0]);
    const float u1 = __builtin_nontemporal_load(&sh1[3*e+1]);
    const float u2 = __builtin_nontemporal_load(&sh1[3*e+2]);
    const float q0 = __builtin_nontemporal_load(&sh2[5*e+0]);
    const float q1 = __builtin_nontemporal_load(&sh2[5*e+1]);
    const float q2 = __builtin_nontemporal_load(&sh2[5*e+2]);
    const float q3 = __builtin_nontemporal_load(&sh2[5*e+3]);
    const float q4 = __builtin_nontemporal_load(&sh2[5*e+4]);

    const float Q00 = -q2*IS30 - q4*IS10;
    const float Q01 =  q1*IS10;
    const float Q02 =  q0*IS10;
    const float Q11 =  2.0f*q2*IS30;
    const float Q12 =  q3*IS10;
    const float Q22 = -q2*IS30 + q4*IS10;

    float4* pr = (float4*)(pay + (size_t)pos * 16);
    pr[0] = make_float4(s, u0, u1, u2);
    pr[1] = make_float4(Q00, Q01, Q02, Q11);
    pr[2] = make_float4(Q12, Q22, __int_as_float(src), 0.f);
    pr[3] = make_float4(0.f, 0.f, 0.f, 0.f);   // full 64B line, one touch
}

// ---------------- aggregation: one WAVE per node, 64 lanes = 8 edges x 8 channels ----
// - zero divergence: loop bounds are wave-uniform; tail handled by masking nf
//   (all 14 accumulator terms are linear in f0/x/y/z)
// - per group-iteration: 8 payload rows = 512B contiguous; 8 node lines in flight
// - payload read with PLAIN loads: it was just written, fits in 256MB L3 -> should
//   be an L3 hit (R0-R3 used nt loads which bypassed allocation -> full HBM fetch)
// - 1-deep pipeline: group g+1 payload + its node vectors issued while computing g
// - end of node: reduce a[14] across jslot lanes via shfl_xor(8,16,32)

#define ACC_STRIDE 15   // 14 used +1 pad to break LDS bank conflicts

__global__ __launch_bounds__(THREADS) void k_agg7(const float* __restrict__ node,   // [N][32]
                                                  const float* __restrict__ nodeT,  // [N][8][4] or null
                                                  const int*   __restrict__ rowptr,
                                                  const float* __restrict__ pay,
                                                  const float* __restrict__ W,
                                                  float*       __restrict__ out,
                                                  int N, int useT) {
    __shared__ float sW[384];
    __shared__ float sAcc[32 * 8 * ACC_STRIDE];
    for (int t = threadIdx.x; t < 384; t += THREADS) sW[t] = W[t];
    __syncthreads();

    constexpr float IS3 = 0.57735026918962576f;
    constexpr float IS6 = 0.40824829046386302f;

    const int lane  = threadIdx.x & 63;
    const int wv    = threadIdx.x >> 6;    // wave 0..3
    const int i     = lane & 7;            // channel
    const int jslot = lane >> 3;           // edge slot 0..7
    const int nbase = blockIdx.x * 32 + wv * 8;

    for (int t = 0; t < 8; ++t) {
        const int n = nbase + t;           // wave-uniform

        float a[14];
        #pragma unroll
        for (int k = 0; k < 14; ++k) a[k] = 0.f;

        if (n < N) {
            const int jbeg = rowptr[n];
            const int jend = rowptr[n + 1];

            if (jbeg < jend) {
                // prologue: group 0 payload + node vec
                int j  = jbeg + jslot;
                int jc = (j < jend) ? j : (jend - 1);
                float mcur = (j < jend) ? 1.f : 0.f;
                const v4f* p = (const v4f*)(pay + (size_t)jc * 16);
                v4f c0 = p[0], c1 = p[1], c2 = p[2];
                int src = __float_as_int(c2[2]);
                v4f nf;
                if (useT) {
                    nf = *(const v4f*)(nodeT + ((size_t)src * 8 + i) * 4);
                } else {
                    const float* nr = node + (size_t)src * 32;
                    nf[0] = nr[i];
                    nf[1] = nr[8 + 3*i + 0];
                    nf[2] = nr[8 + 3*i + 1];
                    nf[3] = nr[8 + 3*i + 2];
                }

                for (int g0 = jbeg; g0 < jend; g0 += 8) {
                    // issue next group's payload (addresses independent of data)
                    const int gn = g0 + 8;
                    const bool more = gn < jend;   // wave-uniform
                    v4f d0, d1, d2; float mnext = 0.f;
                    if (more) {
                        int jn  = gn + jslot;
                        int jnc = (jn < jend) ? jn : (jend - 1);
                        mnext = (jn < jend) ? 1.f : 0.f;
                        const v4f* pn = (const v4f*)(pay + (size_t)jnc * 16);
                        d0 = pn[0]; d1 = pn[1]; d2 = pn[2];
                    }

                    // compute current group (mask tail by scaling node vec)
                    const float f0 = nf[0] * mcur;
                    const float x  = nf[1] * mcur;
                    const float y  = nf[2] * mcur;
                    const float z  = nf[3] * mcur;
                    const float s   = c0[0], u0 = c0[1], u1 = c0[2], u2 = c0[3];
                    const float Q00 = c1[0], Q01 = c1[1], Q02 = c1[2], Q11 = c1[3];
                    const float Q12 = c2[0], Q22 = c2[1];

                    a[0]  += s * f0;
                    a[1]  += u0*x + u1*y + u2*z;
                    a[2]  += s * x;
                    a[3]  += s * y;
                    a[4]  += s * z;
                    a[5]  += f0 * u0;
                    a[6]  += f0 * u1;
                    a[7]  += f0 * u2;
                    a[8]  += u1*z - u2*y;
                    a[9]  += u2*x - u0*z;
                    a[10] += u0*y - u1*x;
                    a[11] += Q00*x + Q01*y + Q02*z;
                    a[12] += Q01*x + Q11*y + Q12*z;
                    a[13] += Q02*x + Q12*y + Q22*z;

                    // rotate: launch node vecs for next group (src just arrived)
                    if (more) {
                        int srcn = __float_as_int(d2[2]);
                        if (useT) {
                            nf = *(const v4f*)(nodeT + ((size_t)srcn * 8 + i) * 4);
                        } else {
                            const float* nrn = node + (size_t)srcn * 32;
                            nf[0] = nrn[i];
                            nf[1] = nrn[8 + 3*i + 0];
                            nf[2] = nrn[8 + 3*i + 1];
                            nf[3] = nrn[8 + 3*i + 2];
                        }
                        c0 = d0; c1 = d1; c2 = d2; mcur = mnext;
                    }
                }
            }
        }

        // reduce across the 8 edge slots (lane bits 3..5); no divergence here
        #pragma unroll
        for (int k = 0; k < 14; ++k) {
            float v = a[k];
            v += __shfl_xor(v, 8);
            v += __shfl_xor(v, 16);
            v += __shfl_xor(v, 32);
            a[k] = v;
        }

        if (n < N && jslot == 0) {
            #pragma unroll
            for (int k = 1; k < 8; ++k) a[k] *= IS3;
            #pragma unroll
            for (int k = 8; k < 11; ++k) a[k] *= IS6;
            float* myAcc = &sAcc[((wv * 8 + t) * 8 + i) * ACC_STRIDE];
            #pragma unroll
            for (int k = 0; k < 14; ++k) myAcc[k] = a[k];
        }
    }
    __syncthreads();

    // per-node postmix (channel-mixing weights), 8 threads per node
    {
        const int nodeSlot = threadIdx.x >> 3;
        const int o        = threadIdx.x & 7;
        const int n        = blockIdx.x * 32 + nodeSlot;
        if (n < N) {
            float o0 = 0.f, ox = 0.f, oy = 0.f, oz = 0.f;
            #pragma unroll
            for (int ii = 0; ii < 8; ++ii) {
                const float* A = &sAcc[(nodeSlot * 8 + ii) * ACC_STRIDE];
                const float w0 = sW[  0 + ii*8 + o];
                const float w1 = sW[ 64 + ii*8 + o];
                const float w2 = sW[128 + ii*8 + o];
                const float w3 = sW[192 + ii*8 + o];
                const float w4 = sW[256 + ii*8 + o];
                const float w5 = sW[320 + ii*8 + o];
                o0 += w0*A[0]  + w3*A[1];
                ox += w1*A[2]  + w2*A[5] + w4*A[8]  + w5*A[11];
                oy += w1*A[3]  + w2*A[6] + w4*A[9]  + w5*A[12];
                oz += w1*A[4]  + w2*A[7] + w4*A[10] + w5*A[13];
            }
            float* orow = out + (size_t)n * 32;
            orow[o]         = o0;
            orow[8 + 3*o+0] = ox;
            orow[8 + 3*o+1] = oy;
            orow[8 + 3*o+2] = oz;
        }
    }
}

// ---------------- fallback: round-1 atomic kernel ----------------

__global__ __launch_bounds__(THREADS) void msg_kernel_atomic(
    const float* __restrict__ node,
    const int*   __restrict__ eidx,
    const float* __restrict__ sh0,
    const float* __restrict__ sh1,
    const float* __restrict__ sh2,
    const float* __restrict__ W,
    float*       __restrict__ out,
    int E)
{
    __shared__ float sW[384];
    for (int t = threadIdx.x; t < 384; t += THREADS) sW[t] = W[t];
    __syncthreads();

    int e = blockIdx.x * THREADS + threadIdx.x;
    if (e >= E) return;

    constexpr float IS3  = 0.57735026918962576f;
    constexpr float IS6  = 0.40824829046386302f;
    constexpr float IS10 = 0.31622776601683794f;
    constexpr float IS30 = 0.18257418583505536f;

    const int src = eidx[e];
    const int tgt = eidx[E + e];

    const float s  = sh0[e];
    const float u0 = sh1[3*e+0], u1 = sh1[3*e+1], u2 = sh1[3*e+2];
    const float q0 = sh2[5*e+0], q1 = sh2[5*e+1], q2 = sh2[5*e+2],
                q3 = sh2[5*e+3], q4 = sh2[5*e+4];

    const float Q00 = -q2*IS30 - q4*IS10;
    const float Q01 =  q1*IS10;
    const float Q02 =  q0*IS10;
    const float Q11 =  2.0f*q2*IS30;
    const float Q12 =  q3*IS10;
    const float Q22 = -q2*IS30 + q4*IS10;

    float f[32];
    {
        const float4* nr = (const float4*)(node + (size_t)src * 32);
        #pragma unroll
        for (int i = 0; i < 8; ++i) {
            float4 v = nr[i];
            f[4*i+0]=v.x; f[4*i+1]=v.y; f[4*i+2]=v.z; f[4*i+3]=v.w;
        }
    }

    float msg[32];
    #pragma unroll
    for (int j = 0; j < 32; ++j) msg[j] = 0.0f;

    const float s13 = s * IS3;

    #pragma unroll
    for (int i = 0; i < 8; ++i) {
        const float f0i = f[i];
        const float x = f[8+3*i+0], y = f[8+3*i+1], z = f[8+3*i+2];
        const float c0  = s * f0i;
        const float c3  = IS3 * (u0*x + u1*y + u2*z);
        const float p2  = IS3 * f0i;
        const float c1x = s13*x, c1y = s13*y, c1z = s13*z;
        const float c2x = p2*u0, c2y = p2*u1, c2z = p2*u2;
        const float c4x = IS6*(u1*z - u2*y);
        const float c4y = IS6*(u2*x - u0*z);
        const float c4z = IS6*(u0*y - u1*x);
        const float c5x = Q00*x + Q01*y + Q02*z;
        const float c5y = Q01*x + Q11*y + Q12*z;
        const float c5z = Q02*x + Q12*y + Q22*z;

        float wr[6][8];
        #pragma unroll
        for (int c = 0; c < 6; ++c) {
            float4 aa = *(const float4*)&sW[c*64 + i*8 + 0];
            float4 bb = *(const float4*)&sW[c*64 + i*8 + 4];
            wr[c][0]=aa.x; wr[c][1]=aa.y; wr[c][2]=aa.z; wr[c][3]=aa.w;
            wr[c][4]=bb.x; wr[c][5]=bb.y; wr[c][6]=bb.z; wr[c][7]=bb.w;
        }

        #pragma unroll
        for (int o = 0; o < 8; ++o) {
            msg[o] += wr[0][o]*c0 + wr[3][o]*c3;
            msg[8+3*o+0] += wr[1][o]*c1x + wr[2][o]*c2x + wr[4][o]*c4x + wr[5][o]*c5x;
            msg[8+3*o+1] += wr[1][o]*c1y + wr[2][o]*c2y + wr[4][o]*c4y + wr[5][o]*c5y;
            msg[8+3*o+2] += wr[1][o]*c1z + wr[2][o]*c2z + wr[4][o]*c4z + wr[5][o]*c5z;
        }
    }

    float* orow = out + (size_t)tgt * 32;
    #pragma unroll
    for (int j = 0; j < 32; ++j) unsafeAtomicAdd(orow + j, msg[j]);
}

// ---------------- host ----------------

extern "C" void kernel_launch(void* const* d_in, const int* in_sizes, int n_in,
                              void* d_out, int out_size, void* d_ws, size_t ws_size,
                              hipStream_t stream) {
    const float* node = (const float*)d_in[0];
    const int*   eidx = (const int*)d_in[1];
    const float* sh0  = (const float*)d_in[2];
    const float* sh1  = (const float*)d_in[3];
    const float* sh2  = (const float*)d_in[4];
    const float* W    = (const float*)d_in[5];
    float* out = (float*)d_out;

    const int E = in_sizes[2];          // sh0 has E elements
    const int N = in_sizes[0] / 32;     // node_irreps is [N, 32]
    const int NB = (N + 1023) / 1024;

    // ws layouts (words):
    //   tier1: rowptr[N+1] | cnt[N] | bsum[1024] | ke[E] | (64B align) pay[16E] | nodeT[32N]
    //   tier2: same without nodeT
    //   tier3: no ke (atomic cursor), no nodeT
    size_t base_w = (size_t)(N + 1) + N + 1024;
    size_t int12  = base_w + (size_t)E;                  // with ke
    size_t pay12  = (int12 + 15) & ~(size_t)15;
    size_t nT1    = pay12 + (size_t)E * 16;              // stays 64B aligned
    size_t need1  = (nT1 + (size_t)N * 32) * sizeof(float);
    size_t need2  = (pay12 + (size_t)E * 16) * sizeof(float);
    size_t pay3   = (base_w + 15) & ~(size_t)15;
    size_t need3  = (pay3 + (size_t)E * 16) * sizeof(float);

    const int gridE = (E + THREADS - 1) / THREADS;

    if (ws_size >= need3 && NB <= 1024) {
        const bool useKe = (ws_size >= need2);
        const bool useT  = (ws_size >= need1);

        int* wsI    = (int*)d_ws;
        int* rowptr = wsI;
        int* cnt    = rowptr + (N + 1);
        int* bsum   = cnt + N;
        int* ke     = useKe ? (bsum + 1024) : nullptr;
        float* pay  = (float*)d_ws + (useKe ? pay12 : pay3);
        float* nodeT = useT ? ((float*)d_ws + nT1) : nullptr;

        hipMemsetAsync(cnt, 0, (size_t)N * sizeof(int), stream);

        if (useKe)
            k_hist2<<<gridE, THREADS, 0, stream>>>(eidx + E, cnt, ke, E);
        else
            k_hist<<<gridE, THREADS, 0, stream>>>(eidx + E, cnt, E);

        if (useT)
            k_ntrans<<<(8 * N + THREADS - 1) / THREADS, THREADS, 0, stream>>>(node, nodeT, 8 * N);

        k_scan_partial<<<NB, THREADS, 0, stream>>>(cnt, bsum, N);
        k_scan_bsum<<<1, 1024, 0, stream>>>(bsum, NB);
        k_scan_final<<<NB, THREADS, 0, stream>>>(cnt, bsum, rowptr, N, E);

        k_scatter4<<<gridE, THREADS, 0, stream>>>(eidx, ke, rowptr, cnt,
                                                  sh0, sh1, sh2, pay, E);

        k_agg7<<<(N + 31) / 32, THREADS, 0, stream>>>(node, nodeT, rowptr, pay, W,
                                                      out, N, useT ? 1 : 0);
    } else {
        hipMemsetAsync(d_out, 0, (size_t)out_size * sizeof(float), stream);
        msg_kernel_atomic<<<gridE, THREADS, 0, stream>>>(
            node, eidx, sh0, sh1, sh2, W, out, E);
    }
}